// Round 7
// baseline (778.431 us; speedup 1.0000x reference)
//
#include <hip/hip_runtime.h>
#include <hip/hip_bf16.h>
#include <math.h>

#define NN 50000
#define NE 800000
#define FD 100
#define HD 128
#define CD 40
#define EPSF 1e-5f
#define NTILE 6250   // NE / 128 exactly
#define GRID_EDGE 512

typedef __attribute__((ext_vector_type(8))) short short8;
typedef __attribute__((ext_vector_type(4))) float f32x4;

__device__ __forceinline__ unsigned short f2bf(float x) {
  union { __hip_bfloat16 h; unsigned short u; } cv;
  cv.h = __float2bfloat16(x);
  return cv.u;
}
__device__ __forceinline__ float bf2f(unsigned short b) {
  return __uint_as_float(((unsigned)b) << 16);
}

// Barrier that only waits on LDS (lgkm) traffic: does NOT drain outstanding
// global stores/atomics (vmcnt) like __syncthreads() does. Safe here because
// in-loop barriers only protect LDS buffer reuse; global atomics need no
// intra-kernel visibility ordering.
__device__ __forceinline__ void bar_lds() {
  asm volatile("s_waitcnt lgkmcnt(0)\n\ts_barrier" ::: "memory");
}

// row_ptr[i] = first edge index with seg_ids >= i
__global__ void k_rowptr(const int* __restrict__ seg, int* __restrict__ rp) {
  int i = blockIdx.x * blockDim.x + threadIdx.x;
  if (i > NN) return;
  int lo = 0, hi = NE;
  while (lo < hi) { int mid = (lo + hi) >> 1; if (seg[mid] < i) lo = mid + 1; else hi = mid; }
  rp[i] = lo;
}

// convert 32 f32 (in 8 float4) -> 4 swizzled short8 LDS writes (row stride 256B)
__device__ __forceinline__ void cvt_write256(const float4* gv, char* rowbase, int q, int sr) {
  const float* vf = (const float*)gv;
#pragma unroll
  for (int h = 0; h < 4; ++h) {
    short8 s;
#pragma unroll
    for (int e = 0; e < 8; ++e) s[e] = (short)f2bf(vf[h * 8 + e]);
    *(short8*)(rowbase + ((q * 64 + h * 16) ^ ((sr & 7) << 4))) = s;
  }
}

// ---------------- pass 1: MFMA edge GEMM -> es/eq row stats + fsum ----------------
// Persistent 512 blocks grid-striding 6250 tiles. Double-buffered A, B in regs,
// ONE lgkm-barrier per tile. Scan: register-batched preload (8/batch).
__global__ __launch_bounds__(512, 4) void k_gemm1(
    const float* __restrict__ nbr, const int* __restrict__ seg,
    const float* __restrict__ W1x,
    float* __restrict__ es, float* __restrict__ eq, float* __restrict__ fsum) {
  __shared__ char lds[65536];     // two 32KB A buffers; buf0 doubles as B staging
  __shared__ int segL[2][128];
  const int tid = threadIdx.x;
  const int sr = tid >> 2, q = tid & 3;
  const int w = tid >> 6, l = tid & 63, lr = l & 15, lh = l >> 4;

  // stage B = W1x (128 x 100 f32) -> bf16 swizzled into buf0 -> registers
  {
    float4 gv[8];
    const float* src = W1x + (size_t)sr * FD;
#pragma unroll
    for (int i4 = 0; i4 < 8; ++i4) {
      const int c = q * 32 + i4 * 4;
      gv[i4] = (c < FD) ? *(const float4*)(src + c) : make_float4(0.f, 0.f, 0.f, 0.f);
    }
    cvt_write256(gv, lds + sr * 256, q, sr);
  }
  __syncthreads();
  short8 bfr[8][4];
#pragma unroll
  for (int nt = 0; nt < 8; ++nt) {
#pragma unroll
    for (int kk = 0; kk < 4; ++kk) {
      const int n = nt * 16 + lr;
      bfr[nt][kk] = *(short8*)(lds + n * 256 + ((lh * 16 + kk * 64) ^ ((n & 7) << 4)));
    }
  }
  __syncthreads();

  // prologue: stage first tile
  {
    const int t0 = blockIdx.x;
    float4 gv[8];
    const float* src = nbr + (size_t)(t0 * 128 + sr) * FD;
#pragma unroll
    for (int i4 = 0; i4 < 8; ++i4) {
      const int c = q * 32 + i4 * 4;
      gv[i4] = (c < FD) ? *(const float4*)(src + c) : make_float4(0.f, 0.f, 0.f, 0.f);
    }
    cvt_write256(gv, lds + sr * 256, q, sr);
    if (tid < 128) segL[0][tid] = seg[t0 * 128 + tid];
  }
  int cur = 0;
  for (int t = blockIdx.x; t < NTILE; t += GRID_EDGE) {
    const int tn = t + GRID_EDGE;
    float4 gv[8];
    int sgn = 0;
    if (tn < NTILE) {  // issue next tile's loads early (not drained by bar_lds)
      const float* src = nbr + (size_t)(tn * 128 + sr) * FD;
#pragma unroll
      for (int i4 = 0; i4 < 8; ++i4) {
        const int c = q * 32 + i4 * 4;
        gv[i4] = (c < FD) ? *(const float4*)(src + c) : make_float4(0.f, 0.f, 0.f, 0.f);
      }
      if (tid < 128) sgn = seg[tn * 128 + tid];
    }
    bar_lds();  // buf[cur]+segL[cur] visible; prev scan of buf[cur^1] complete
    const char* bufc = lds + cur * 32768;
    short8 af[4];
    const int arow = w * 16 + lr;
#pragma unroll
    for (int kk = 0; kk < 4; ++kk)
      af[kk] = *(short8*)(bufc + arow * 256 + ((lh * 16 + kk * 64) ^ ((arow & 7) << 4)));
    // stage next tile into buf[cur^1] (frees gv; disjoint from bufc reads)
    if (tn < NTILE) {
      cvt_write256(gv, lds + (cur ^ 1) * 32768 + sr * 256, q, sr);
      if (tid < 128) segL[cur ^ 1][tid] = sgn;
    }

    const size_t rowb = (size_t)t * 128;
    float rs[4] = {0.f, 0.f, 0.f, 0.f}, rq[4] = {0.f, 0.f, 0.f, 0.f};
#pragma unroll
    for (int nt = 0; nt < 8; ++nt) {
      f32x4 acc = {0.f, 0.f, 0.f, 0.f};
#pragma unroll
      for (int kk = 0; kk < 4; ++kk)
        acc = __builtin_amdgcn_mfma_f32_16x16x32_bf16(af[kk], bfr[nt][kk], acc, 0, 0, 0);
#pragma unroll
      for (int r = 0; r < 4; ++r) {
        const float val = acc[r];
        rs[r] += val;
        rq[r] = fmaf(val, val, rq[r]);
      }
    }
#pragma unroll
    for (int r = 0; r < 4; ++r) {
      float a = rs[r], b = rq[r];
#pragma unroll
      for (int off = 1; off < 16; off <<= 1) { a += __shfl_xor(a, off); b += __shfl_xor(b, off); }
      if (lr == 0) {
        const size_t rg = rowb + w * 16 + lh * 4 + r;
        es[rg] = a; eq[rg] = b;  // fire-and-forget, never drained in-loop
      }
    }
    // fsum scan of bf16 A-tile: register-batched, quarter-split segmented sum
    {
      const int qq = tid >> 7, j = tid & 127;
      if (j < FD) {
        const int r0 = qq * 32;
        const int* sl = segL[cur];
        int curn = sl[r0];
        float acc = 0.f;
        bool inside = false;
#pragma unroll
        for (int b8 = 0; b8 < 4; ++b8) {
          float vals[8];
#pragma unroll
          for (int k = 0; k < 8; ++k) {
            const int row = r0 + b8 * 8 + k;
            vals[k] = bf2f(*(const unsigned short*)(bufc + row * 256 + ((j * 2) ^ ((row & 7) << 4))));
          }
#pragma unroll
          for (int k = 0; k < 8; ++k) {
            const int nd = sl[r0 + b8 * 8 + k];
            if (nd != curn) {
              float* dst = fsum + (size_t)curn * FD + j;
              if (inside) *dst = acc; else atomicAdd(dst, acc);
              inside = true; acc = 0.f; curn = nd;
            }
            acc += vals[k];
          }
        }
        atomicAdd(fsum + (size_t)curn * FD + j, acc);
      }
    }
    cur ^= 1;
  }
}

// per-node BN stats from per-edge sums: sm, inv, rc
__global__ void k_nodestats(const int* __restrict__ rp, const float* __restrict__ es,
                            const float* __restrict__ eq, float2* __restrict__ smi,
                            float* __restrict__ rcv) {
  const int i = blockIdx.x * blockDim.x + threadIdx.x;
  if (i >= NN) return;
  const int s = rp[i], e = rp[i + 1];
  float S = 0.f, Q = 0.f;
  for (int ed = s; ed < e; ++ed) { S += es[ed]; Q += eq[ed]; }
  const int cnt = e - s;
  const float ne = fmaxf((float)cnt * (float)HD, 1.f);
  const float sm = S / ne;
  const float var = Q / ne - sm * sm;
  smi[i] = make_float2(sm, rsqrtf(var + EPSF));
  rcv[i] = 1.f / (float)(cnt > 0 ? cnt : 1);
}

// ---------------- pass 2: recompute MFMA, BN+ReLU in-register, scan -> f2sum ----------------
// Persistent 512 blocks. Single A buffer + P buffer, TWO lgkm-barriers per tile.
__global__ __launch_bounds__(512, 4) void k_fuse2(
    const float* __restrict__ nbr, const int* __restrict__ seg,
    const float* __restrict__ W1x, const float2* __restrict__ smi,
    const float* __restrict__ g1p, const float* __restrict__ b1p,
    float* __restrict__ f2sum) {
  __shared__ char A[32768];
  __shared__ char P[32768];
  __shared__ int segL[2][128];
  __shared__ float2 smrow[2][128];
  const int tid = threadIdx.x;
  const int sr = tid >> 2, q = tid & 3;
  const int w = tid >> 6, l = tid & 63, lr = l & 15, lh = l >> 4;
  const float g1 = g1p[0], b1 = b1p[0];

  // stage B = W1x transiently in A -> registers
  {
    float4 gv[8];
    const float* src = W1x + (size_t)sr * FD;
#pragma unroll
    for (int i4 = 0; i4 < 8; ++i4) {
      const int c = q * 32 + i4 * 4;
      gv[i4] = (c < FD) ? *(const float4*)(src + c) : make_float4(0.f, 0.f, 0.f, 0.f);
    }
    cvt_write256(gv, A + sr * 256, q, sr);
  }
  __syncthreads();
  short8 bfr[8][4];
#pragma unroll
  for (int nt = 0; nt < 8; ++nt) {
#pragma unroll
    for (int kk = 0; kk < 4; ++kk) {
      const int n = nt * 16 + lr;
      bfr[nt][kk] = *(short8*)(A + n * 256 + ((lh * 16 + kk * 64) ^ ((n & 7) << 4)));
    }
  }
  __syncthreads();

  // prologue: stage first tile
  {
    const int t0 = blockIdx.x;
    float4 gv[8];
    const float* src = nbr + (size_t)(t0 * 128 + sr) * FD;
#pragma unroll
    for (int i4 = 0; i4 < 8; ++i4) {
      const int c = q * 32 + i4 * 4;
      gv[i4] = (c < FD) ? *(const float4*)(src + c) : make_float4(0.f, 0.f, 0.f, 0.f);
    }
    cvt_write256(gv, A + sr * 256, q, sr);
    if (tid < 128) {
      const int nd = seg[t0 * 128 + tid];
      segL[0][tid] = nd;
      smrow[0][tid] = smi[nd];
    }
  }
  int cur = 0;
  for (int t = blockIdx.x; t < NTILE; t += GRID_EDGE) {
    const int tn = t + GRID_EDGE;
    float4 gv[8];
    int sgn = 0;
    float2 smn = make_float2(0.f, 0.f);
    if (tn < NTILE) {
      const float* src = nbr + (size_t)(tn * 128 + sr) * FD;
#pragma unroll
      for (int i4 = 0; i4 < 8; ++i4) {
        const int c = q * 32 + i4 * 4;
        gv[i4] = (c < FD) ? *(const float4*)(src + c) : make_float4(0.f, 0.f, 0.f, 0.f);
      }
      if (tid < 128) { sgn = seg[tn * 128 + tid]; smn = smi[sgn]; }
    }
    bar_lds();  // A + segL/smrow[cur] visible; prev P-scan reads complete
    short8 af[4];
    const int arow = w * 16 + lr;
#pragma unroll
    for (int kk = 0; kk < 4; ++kk)
      af[kk] = *(short8*)(A + arow * 256 + ((lh * 16 + kk * 64) ^ ((arow & 7) << 4)));
    float2 mi[4];
#pragma unroll
    for (int r = 0; r < 4; ++r) mi[r] = smrow[cur][w * 16 + lh * 4 + r];
#pragma unroll
    for (int nt = 0; nt < 8; ++nt) {
      f32x4 acc = {0.f, 0.f, 0.f, 0.f};
#pragma unroll
      for (int kk = 0; kk < 4; ++kk)
        acc = __builtin_amdgcn_mfma_f32_16x16x32_bf16(af[kk], bfr[nt][kk], acc, 0, 0, 0);
      const int col = nt * 16 + lr;
#pragma unroll
      for (int r = 0; r < 4; ++r) {
        const int row = w * 16 + lh * 4 + r;
        const float v = fmaxf(fmaf(g1, (acc[r] - mi[r].x) * mi[r].y, b1), 0.f);
        *(unsigned short*)(P + row * 256 + ((col * 2) ^ ((row & 7) << 4))) = f2bf(v);
      }
    }
    bar_lds();  // P complete; all af reads done -> A free for restage
    if (tn < NTILE) {
      cvt_write256(gv, A + sr * 256, q, sr);
      if (tid < 128) { segL[cur ^ 1][tid] = sgn; smrow[cur ^ 1][tid] = smn; }
    }
    // f2sum scan of P: register-batched, quarter-split segmented sum
    {
      const int qq = tid >> 7, j = tid & 127;
      const int r0 = qq * 32;
      const int* sl = segL[cur];
      int curn = sl[r0];
      float acc = 0.f;
      bool inside = false;
#pragma unroll
      for (int b8 = 0; b8 < 4; ++b8) {
        float vals[8];
#pragma unroll
        for (int k = 0; k < 8; ++k) {
          const int row = r0 + b8 * 8 + k;
          vals[k] = bf2f(*(const unsigned short*)(P + row * 256 + ((j * 2) ^ ((row & 7) << 4))));
        }
#pragma unroll
        for (int k = 0; k < 8; ++k) {
          const int nd = sl[r0 + b8 * 8 + k];
          if (nd != curn) {
            float* dst = f2sum + (size_t)curn * HD + j;
            if (inside) *dst = acc; else atomicAdd(dst, acc);
            inside = true; acc = 0.f; curn = nd;
          }
          acc += vals[k];
        }
      }
      atomicAdd(f2sum + (size_t)curn * HD + j, acc);
    }
    cur ^= 1;
  }
}

// ---------------- node GEMMs (MFMA, K=256 two-half) ----------------
template <bool L2>
__global__ __launch_bounds__(512) void k_ngemm(
    const float* __restrict__ P1, const float* __restrict__ P2,
    const float* __restrict__ rcv,
    const float* __restrict__ WA, const float* __restrict__ WB,
    const float* __restrict__ stats_in,
    const float* __restrict__ gp, const float* __restrict__ bp,
    float* __restrict__ out, float* __restrict__ so) {
  constexpr int KH = L2 ? HD : FD;
  __shared__ char lds[131072];
  __shared__ float sred[16];
  const int tid = threadIdx.x;
  float a1 = 1.f, c1 = 0.f;
  if (L2) {
    const float m = stats_in[0] * (1.f / ((float)NN * (float)HD));
    const float var = stats_in[1] * (1.f / ((float)NN * (float)HD)) - m * m;
    const float inv = rsqrtf(var + EPSF);
    const float g = gp[0], bb = bp[0];
    a1 = g * inv; c1 = bb - g * m * inv;
  }
  const int sr = tid >> 2, q = tid & 3;
  const size_t rg = (size_t)blockIdx.x * 128 + sr;
  {
    const bool half2 = (q >= 2);
    const int cbase = (q & 1) * 64;
    const float* src = (half2 ? P2 : P1) + rg * KH;
    const float sc = half2 ? ((rg < NN) ? rcv[rg] : 0.f) : 1.f;
    float v[64];
#pragma unroll
    for (int i4 = 0; i4 < 16; ++i4) {
      const int c = cbase + i4 * 4;
      float4 t = make_float4(0.f, 0.f, 0.f, 0.f);
      if (rg < NN && c < KH) t = *(const float4*)(src + c);
      float e0 = t.x, e1 = t.y, e2 = t.z, e3 = t.w;
      if (half2) { e0 *= sc; e1 *= sc; e2 *= sc; e3 *= sc; }
      else if (L2) {
        e0 = fmaxf(fmaf(a1, e0, c1), 0.f); e1 = fmaxf(fmaf(a1, e1, c1), 0.f);
        e2 = fmaxf(fmaf(a1, e2, c1), 0.f); e3 = fmaxf(fmaf(a1, e3, c1), 0.f);
      }
      v[i4 * 4 + 0] = e0; v[i4 * 4 + 1] = e1; v[i4 * 4 + 2] = e2; v[i4 * 4 + 3] = e3;
    }
    char* db = lds + sr * 512;
#pragma unroll
    for (int h = 0; h < 8; ++h) {
      short8 s8;
#pragma unroll
      for (int e = 0; e < 8; ++e) s8[e] = (short)f2bf(v[h * 8 + e]);
      *(short8*)(db + ((q * 128 + h * 16) ^ ((sr & 7) << 4))) = s8;
    }
  }
  {
    const bool half2 = (q >= 2);
    const int cbase = (q & 1) * 64;
    const float* src = (half2 ? WB : WA) + (size_t)sr * KH;
    float v[64];
#pragma unroll
    for (int i4 = 0; i4 < 16; ++i4) {
      const int c = cbase + i4 * 4;
      float4 t = make_float4(0.f, 0.f, 0.f, 0.f);
      if (c < KH) t = *(const float4*)(src + c);
      v[i4 * 4 + 0] = t.x; v[i4 * 4 + 1] = t.y; v[i4 * 4 + 2] = t.z; v[i4 * 4 + 3] = t.w;
    }
    char* db = lds + 65536 + sr * 512;
#pragma unroll
    for (int h = 0; h < 8; ++h) {
      short8 s8;
#pragma unroll
      for (int e = 0; e < 8; ++e) s8[e] = (short)f2bf(v[h * 8 + e]);
      *(short8*)(db + ((q * 128 + h * 16) ^ ((sr & 7) << 4))) = s8;
    }
  }
  __syncthreads();
  const int w = tid >> 6, l = tid & 63, lr = l & 15, lh = l >> 4;
  short8 af[8];
  const int arow = w * 16 + lr;
#pragma unroll
  for (int kk = 0; kk < 8; ++kk)
    af[kk] = *(short8*)(lds + arow * 512 + ((lh * 16 + kk * 64) ^ ((arow & 7) << 4)));
  float ls = 0.f, lsq = 0.f;
  const char* B = lds + 65536;
#pragma unroll
  for (int nt = 0; nt < 8; ++nt) {
    f32x4 acc = {0.f, 0.f, 0.f, 0.f};
#pragma unroll
    for (int kk = 0; kk < 8; ++kk) {
      const int n = nt * 16 + lr;
      short8 bfg = *(const short8*)(B + n * 512 + ((lh * 16 + kk * 64) ^ ((n & 7) << 4)));
      acc = __builtin_amdgcn_mfma_f32_16x16x32_bf16(af[kk], bfg, acc, 0, 0, 0);
    }
    const int col = nt * 16 + lr;
#pragma unroll
    for (int r = 0; r < 4; ++r) {
      const float val = acc[r];
      const size_t rg2 = (size_t)blockIdx.x * 128 + w * 16 + lh * 4 + r;
      if (rg2 < NN) out[rg2 * HD + col] = val;
      ls += val;
      lsq = fmaf(val, val, lsq);
    }
  }
#pragma unroll
  for (int off = 32; off > 0; off >>= 1) { ls += __shfl_down(ls, off); lsq += __shfl_down(lsq, off); }
  if ((tid & 63) == 0) { sred[(tid >> 6) * 2] = ls; sred[(tid >> 6) * 2 + 1] = lsq; }
  __syncthreads();
  if (tid == 0) {
    float S = 0.f, Q = 0.f;
#pragma unroll
    for (int i = 0; i < 8; ++i) { S += sred[i * 2]; Q += sred[i * 2 + 1]; }
    atomicAdd(&so[0], S);
    atomicAdd(&so[1], Q);
  }
}

// ---------------- classifier: out = bnrelu(h2) @ Wc^T + bc ----------------
__global__ __launch_bounds__(512) void k_cls(
    const float* __restrict__ h2, const float* __restrict__ Wc,
    const float* __restrict__ bc, const float* __restrict__ stats,
    const float* __restrict__ gp, const float* __restrict__ bp,
    float* __restrict__ out) {
  __shared__ char lds[45056];
  const int tid = threadIdx.x;
  const float m = stats[0] * (1.f / ((float)NN * (float)HD));
  const float var = stats[1] * (1.f / ((float)NN * (float)HD)) - m * m;
  const float inv = rsqrtf(var + EPSF);
  const float g = gp[0], bb = bp[0];
  const float a2 = g * inv, c2 = bb - g * m * inv;
  const int sr = tid >> 2, q = tid & 3;
  const size_t rg = (size_t)blockIdx.x * 128 + sr;
  {
    float4 gv[8];
#pragma unroll
    for (int i4 = 0; i4 < 8; ++i4) {
      const int c = q * 32 + i4 * 4;
      float4 t = (rg < NN) ? *(const float4*)(h2 + rg * HD + c) : make_float4(0.f, 0.f, 0.f, 0.f);
      t.x = fmaxf(fmaf(a2, t.x, c2), 0.f); t.y = fmaxf(fmaf(a2, t.y, c2), 0.f);
      t.z = fmaxf(fmaf(a2, t.z, c2), 0.f); t.w = fmaxf(fmaf(a2, t.w, c2), 0.f);
      gv[i4] = t;
    }
    cvt_write256(gv, lds + sr * 256, q, sr);
  }
  if (tid < 192) {
    const int bn = tid >> 2, bq = tid & 3;
    float4 gv[8];
#pragma unroll
    for (int i4 = 0; i4 < 8; ++i4) {
      const int c = bq * 32 + i4 * 4;
      gv[i4] = (bn < CD) ? *(const float4*)(Wc + (size_t)bn * HD + c) : make_float4(0.f, 0.f, 0.f, 0.f);
    }
    cvt_write256(gv, lds + 32768 + bn * 256, bq, bn);
  }
  __syncthreads();
  const int w = tid >> 6, l = tid & 63, lr = l & 15, lh = l >> 4;
  short8 af[4];
  const int arow = w * 16 + lr;
#pragma unroll
  for (int kk = 0; kk < 4; ++kk)
    af[kk] = *(short8*)(lds + arow * 256 + ((lh * 16 + kk * 64) ^ ((arow & 7) << 4)));
#pragma unroll
  for (int nt = 0; nt < 3; ++nt) {
    f32x4 acc = {0.f, 0.f, 0.f, 0.f};
#pragma unroll
    for (int kk = 0; kk < 4; ++kk) {
      const int n = nt * 16 + lr;
      short8 bfg = *(const short8*)(lds + 32768 + n * 256 + ((lh * 16 + kk * 64) ^ ((n & 7) << 4)));
      acc = __builtin_amdgcn_mfma_f32_16x16x32_bf16(af[kk], bfg, acc, 0, 0, 0);
    }
    const int col = nt * 16 + lr;
    if (col < CD) {
      const float bias = bc[col];
#pragma unroll
      for (int r = 0; r < 4; ++r) {
        const size_t rg2 = (size_t)blockIdx.x * 128 + w * 16 + lh * 4 + r;
        if (rg2 < NN) out[rg2 * CD + col] = acc[r] + bias;
      }
    }
  }
}

extern "C" void kernel_launch(void* const* d_in, const int* in_sizes, int n_in,
                              void* d_out, int out_size, void* d_ws, size_t ws_size,
                              hipStream_t stream) {
  const float* x   = (const float*)d_in[0];
  const float* nbr = (const float*)d_in[1];
  const int*   seg = (const int*)d_in[2];
  const float* W1x = (const float*)d_in[3];
  const float* W1n = (const float*)d_in[4];
  const float* g1  = (const float*)d_in[5];
  const float* b1  = (const float*)d_in[6];
  const float* W2x = (const float*)d_in[7];
  const float* W2n = (const float*)d_in[8];
  const float* g2  = (const float*)d_in[9];
  const float* b2  = (const float*)d_in[10];
  const float* Wc  = (const float*)d_in[11];
  const float* bc  = (const float*)d_in[12];
  float* out = (float*)d_out;

  char* p = (char*)d_ws;
  auto alloc = [&](size_t bytes) {
    char* q = p;
    p += (bytes + 255) & ~(size_t)255;
    return q;
  };
  int*    rp    = (int*)   alloc(sizeof(int) * (NN + 1));
  float*  fsum  = (float*) alloc(sizeof(float) * (size_t)NN * FD);
  float*  f2sum = (float*) alloc(sizeof(float) * (size_t)NN * HD);
  float*  hpre  = (float*) alloc(sizeof(float) * (size_t)NN * HD);
  float*  h2    = (float*) alloc(sizeof(float) * (size_t)NN * HD);
  float*  stats = (float*) alloc(sizeof(float) * 4);
  float*  es    = (float*) alloc(sizeof(float) * (size_t)NE);
  float*  eq    = (float*) alloc(sizeof(float) * (size_t)NE);
  float2* smi   = (float2*)alloc(sizeof(float2) * (size_t)NN);
  float*  rcv   = (float*) alloc(sizeof(float) * (size_t)NN);

  hipMemsetAsync(stats, 0, sizeof(float) * 4, stream);
  hipMemsetAsync(fsum, 0, sizeof(float) * (size_t)NN * FD, stream);
  hipMemsetAsync(f2sum, 0, sizeof(float) * (size_t)NN * HD, stream);

  k_rowptr<<<(NN + 256) / 256, 256, 0, stream>>>(seg, rp);
  k_gemm1<<<GRID_EDGE, 512, 0, stream>>>(nbr, seg, W1x, es, eq, fsum);
  k_nodestats<<<(NN + 255) / 256, 256, 0, stream>>>(rp, es, eq, smi, rcv);
  k_fuse2<<<GRID_EDGE, 512, 0, stream>>>(nbr, seg, W1x, smi, g1, b1, f2sum);
  k_ngemm<false><<<391, 512, 0, stream>>>(x, fsum, rcv, W1x, W1n, stats, g1, b1, hpre, stats);
  k_ngemm<true><<<391, 512, 0, stream>>>(hpre, f2sum, rcv, W2x, W2n, stats, g1, b1, h2, stats + 2);
  k_cls<<<391, 512, 0, stream>>>(h2, Wc, bc, stats + 2, g2, b2, out);
}

// Round 8
// 447.087 us; speedup vs baseline: 1.7411x; 1.7411x over previous
//
#include <hip/hip_runtime.h>
#include <hip/hip_bf16.h>
#include <math.h>

#define NN 50000
#define NE 800000
#define FD 100
#define HD 128
#define CD 40
#define EPSF 1e-5f
#define NTILE 6250    // NE / 128 exactly
#define GRID_EDGE 256
#define NT_NODE 391   // ceil(NN/128)

typedef __attribute__((ext_vector_type(8))) short short8;
typedef __attribute__((ext_vector_type(4))) float f32x4;

__device__ __forceinline__ unsigned short f2bf(float x) {
  union { __hip_bfloat16 h; unsigned short u; } cv;
  cv.h = __float2bfloat16(x);
  return cv.u;
}
__device__ __forceinline__ float bf2f(unsigned short b) {
  return __uint_as_float(((unsigned)b) << 16);
}

// Barrier that only waits on LDS (lgkm) traffic: does NOT drain outstanding
// global stores/atomics/loads (vmcnt) like __syncthreads() does. Safe where
// barriers only order LDS buffer reuse; register deps on global loads are
// tracked by compiler-inserted vmcnt waits at use.
__device__ __forceinline__ void bar_lds() {
  asm volatile("s_waitcnt lgkmcnt(0)\n\ts_barrier" ::: "memory");
}

// row_ptr[i] = first edge index with seg_ids >= i
__global__ void k_rowptr(const int* __restrict__ seg, int* __restrict__ rp) {
  int i = blockIdx.x * blockDim.x + threadIdx.x;
  if (i > NN) return;
  int lo = 0, hi = NE;
  while (lo < hi) { int mid = (lo + hi) >> 1; if (seg[mid] < i) lo = mid + 1; else hi = mid; }
  rp[i] = lo;
}

// convert 32 f32 (in 8 float4) -> 4 swizzled short8 LDS writes (row stride 256B)
__device__ __forceinline__ void cvt_write256(const float4* gv, char* rowbase, int q, int sr) {
  const float* vf = (const float*)gv;
#pragma unroll
  for (int h = 0; h < 4; ++h) {
    short8 s;
#pragma unroll
    for (int e = 0; e < 8; ++e) s[e] = (short)f2bf(vf[h * 8 + e]);
    *(short8*)(rowbase + ((q * 64 + h * 16) ^ ((sr & 7) << 4))) = s;
  }
}

// load one 128-row x FD f32 tile row-quarter into gv (masked to FD cols)
__device__ __forceinline__ void load_quarters(const float* src, int q, float4* gv) {
#pragma unroll
  for (int i4 = 0; i4 < 8; ++i4) {
    const int c = q * 32 + i4 * 4;
    gv[i4] = (c < FD) ? *(const float4*)(src + c) : make_float4(0.f, 0.f, 0.f, 0.f);
  }
}

// ---------------- pass 1: MFMA edge GEMM -> es/eq row stats + fsum ----------------
// LDS: B (32KB, resident) + A double-buffer (2x32KB) = 96KB -> 1 block/CU.
// Persistent 256 blocks; B-fragments read from LDS per MFMA (no giant reg array,
// no spill). One lgkm-barrier per tile; restage after scan (max vmcnt slack).
__global__ __launch_bounds__(512, 2) void k_gemm1(
    const float* __restrict__ nbr, const int* __restrict__ seg,
    const float* __restrict__ W1x,
    float* __restrict__ es, float* __restrict__ eq, float* __restrict__ fsum) {
  __shared__ char lds[98304];   // [0,32K)=B  [32K,64K)=A0  [64K,96K)=A1
  __shared__ int segL[2][128];
  const int tid = threadIdx.x;
  const int sr = tid >> 2, q = tid & 3;
  const int w = tid >> 6, l = tid & 63, lr = l & 15, lh = l >> 4;

  // stage B = W1x (128 x 100 f32) -> bf16 swizzled, resident for whole kernel
  {
    float4 gv[8];
    load_quarters(W1x + (size_t)sr * FD, q, gv);
    cvt_write256(gv, lds + sr * 256, q, sr);
  }
  // prologue: stage first tile into A0
  {
    float4 gv[8];
    load_quarters(nbr + (size_t)(blockIdx.x * 128 + sr) * FD, q, gv);
    if (tid < 128) segL[0][tid] = seg[blockIdx.x * 128 + tid];
    __syncthreads();  // B writes visible before any B-frag read
    cvt_write256(gv, lds + 32768 + sr * 256, q, sr);
  }
  int cur = 0;
  for (int t = blockIdx.x; t < NTILE; t += GRID_EDGE) {
    const int tn = t + GRID_EDGE;
    float4 gv[8];
    int sgn = 0;
    if (tn < NTILE) {  // issue next tile's global loads early
      load_quarters(nbr + (size_t)(tn * 128 + sr) * FD, q, gv);
      if (tid < 128) sgn = seg[tn * 128 + tid];
    }
    bar_lds();  // A[cur]+segL[cur] visible; prev reads of A[cur^1] done
    const char* bufc = lds + 32768 + cur * 32768;
    short8 af[4];
    const int arow = w * 16 + lr;
#pragma unroll
    for (int kk = 0; kk < 4; ++kk)
      af[kk] = *(const short8*)(bufc + arow * 256 + ((lh * 16 + kk * 64) ^ ((arow & 7) << 4)));

    const size_t rowb = (size_t)t * 128;
    float rs[4] = {0.f, 0.f, 0.f, 0.f}, rq[4] = {0.f, 0.f, 0.f, 0.f};
#pragma unroll
    for (int nt = 0; nt < 8; ++nt) {
      f32x4 acc = {0.f, 0.f, 0.f, 0.f};
#pragma unroll
      for (int kk = 0; kk < 4; ++kk) {
        const int n = nt * 16 + lr;
        const short8 bfg = *(const short8*)(lds + n * 256 + ((lh * 16 + kk * 64) ^ ((n & 7) << 4)));
        acc = __builtin_amdgcn_mfma_f32_16x16x32_bf16(af[kk], bfg, acc, 0, 0, 0);
      }
#pragma unroll
      for (int r = 0; r < 4; ++r) {
        const float val = acc[r];
        rs[r] += val;
        rq[r] = fmaf(val, val, rq[r]);
      }
    }
#pragma unroll
    for (int r = 0; r < 4; ++r) {
      float a = rs[r], b = rq[r];
#pragma unroll
      for (int off = 1; off < 16; off <<= 1) { a += __shfl_xor(a, off); b += __shfl_xor(b, off); }
      if (lr == 0) {
        const size_t rg = rowb + w * 16 + lh * 4 + r;
        es[rg] = a; eq[rg] = b;  // fire-and-forget; never drained in-loop
      }
    }
    // fsum scan of bf16 A-tile: register-batched, quarter-split segmented sum
    {
      const int qq = tid >> 7, j = tid & 127;
      if (j < FD) {
        const int r0 = qq * 32;
        const int* sl = segL[cur];
        int curn = sl[r0];
        float acc = 0.f;
        bool inside = false;
#pragma unroll
        for (int b8 = 0; b8 < 4; ++b8) {
          float vals[8];
#pragma unroll
          for (int k = 0; k < 8; ++k) {
            const int row = r0 + b8 * 8 + k;
            vals[k] = bf2f(*(const unsigned short*)(bufc + row * 256 + ((j * 2) ^ ((row & 7) << 4))));
          }
#pragma unroll
          for (int k = 0; k < 8; ++k) {
            const int nd = sl[r0 + b8 * 8 + k];
            if (nd != curn) {
              float* dst = fsum + (size_t)curn * FD + j;
              if (inside) *dst = acc; else atomicAdd(dst, acc);
              inside = true; acc = 0.f; curn = nd;
            }
            acc += vals[k];
          }
        }
        atomicAdd(fsum + (size_t)curn * FD + j, acc);
      }
    }
    // restage next tile into A[cur^1] LAST (gv's vmcnt wait has full-phase slack)
    if (tn < NTILE) {
      cvt_write256(gv, lds + 32768 + (cur ^ 1) * 32768 + sr * 256, q, sr);
      if (tid < 128) segL[cur ^ 1][tid] = sgn;
    }
    cur ^= 1;
  }
}

// per-node BN stats from per-edge sums: sm, inv, rc
__global__ void k_nodestats(const int* __restrict__ rp, const float* __restrict__ es,
                            const float* __restrict__ eq, float2* __restrict__ smi,
                            float* __restrict__ rcv) {
  const int i = blockIdx.x * blockDim.x + threadIdx.x;
  if (i >= NN) return;
  const int s = rp[i], e = rp[i + 1];
  float S = 0.f, Q = 0.f;
  for (int ed = s; ed < e; ++ed) { S += es[ed]; Q += eq[ed]; }
  const int cnt = e - s;
  const float ne = fmaxf((float)cnt * (float)HD, 1.f);
  const float sm = S / ne;
  const float var = Q / ne - sm * sm;
  smi[i] = make_float2(sm, rsqrtf(var + EPSF));
  rcv[i] = 1.f / (float)(cnt > 0 ? cnt : 1);
}

// ---------------- pass 2: recompute MFMA, BN+ReLU, scan -> f2sum ----------------
// LDS: B (32KB) + A (32KB) + P (32KB) = 96KB. Two lgkm-barriers per tile.
__global__ __launch_bounds__(512, 2) void k_fuse2(
    const float* __restrict__ nbr, const int* __restrict__ seg,
    const float* __restrict__ W1x, const float2* __restrict__ smi,
    const float* __restrict__ g1p, const float* __restrict__ b1p,
    float* __restrict__ f2sum) {
  __shared__ char lds[98304];   // [0,32K)=B  [32K,64K)=A  [64K,96K)=P
  __shared__ int segL[2][128];
  __shared__ float2 smrow[2][128];
  const int tid = threadIdx.x;
  const int sr = tid >> 2, q = tid & 3;
  const int w = tid >> 6, l = tid & 63, lr = l & 15, lh = l >> 4;
  const float g1 = g1p[0], b1 = b1p[0];
  char* A = lds + 32768;
  char* P = lds + 65536;

  // stage B (resident)
  {
    float4 gv[8];
    load_quarters(W1x + (size_t)sr * FD, q, gv);
    cvt_write256(gv, lds + sr * 256, q, sr);
  }
  // prologue: stage first tile into A
  {
    float4 gv[8];
    load_quarters(nbr + (size_t)(blockIdx.x * 128 + sr) * FD, q, gv);
    if (tid < 128) {
      const int nd = seg[blockIdx.x * 128 + tid];
      segL[0][tid] = nd;
      smrow[0][tid] = smi[nd];
    }
    __syncthreads();
    cvt_write256(gv, A + sr * 256, q, sr);
  }
  int cur = 0;
  for (int t = blockIdx.x; t < NTILE; t += GRID_EDGE) {
    const int tn = t + GRID_EDGE;
    float4 gv[8];
    int sgn = 0;
    float2 smn = make_float2(0.f, 0.f);
    if (tn < NTILE) {
      load_quarters(nbr + (size_t)(tn * 128 + sr) * FD, q, gv);
      if (tid < 128) { sgn = seg[tn * 128 + tid]; smn = smi[sgn]; }
    }
    bar_lds();  // A + segL/smrow[cur] visible; prev P-scan reads done
    short8 af[4];
    const int arow = w * 16 + lr;
#pragma unroll
    for (int kk = 0; kk < 4; ++kk)
      af[kk] = *(const short8*)(A + arow * 256 + ((lh * 16 + kk * 64) ^ ((arow & 7) << 4)));
    float2 mi[4];
#pragma unroll
    for (int r = 0; r < 4; ++r) mi[r] = smrow[cur][w * 16 + lh * 4 + r];
#pragma unroll
    for (int nt = 0; nt < 8; ++nt) {
      f32x4 acc = {0.f, 0.f, 0.f, 0.f};
#pragma unroll
      for (int kk = 0; kk < 4; ++kk) {
        const int n = nt * 16 + lr;
        const short8 bfg = *(const short8*)(lds + n * 256 + ((lh * 16 + kk * 64) ^ ((n & 7) << 4)));
        acc = __builtin_amdgcn_mfma_f32_16x16x32_bf16(af[kk], bfg, acc, 0, 0, 0);
      }
      const int col = nt * 16 + lr;
#pragma unroll
      for (int r = 0; r < 4; ++r) {
        const int row = w * 16 + lh * 4 + r;
        const float v = fmaxf(fmaf(g1, (acc[r] - mi[r].x) * mi[r].y, b1), 0.f);
        *(unsigned short*)(P + row * 256 + ((col * 2) ^ ((row & 7) << 4))) = f2bf(v);
      }
    }
    bar_lds();  // P complete; all af/B reads drained -> A free for restage
    // f2sum scan of P: register-batched, quarter-split segmented sum
    {
      const int qq = tid >> 7, j = tid & 127;
      const int r0 = qq * 32;
      const int* sl = segL[cur];
      int curn = sl[r0];
      float acc = 0.f;
      bool inside = false;
#pragma unroll
      for (int b8 = 0; b8 < 4; ++b8) {
        float vals[8];
#pragma unroll
        for (int k = 0; k < 8; ++k) {
          const int row = r0 + b8 * 8 + k;
          vals[k] = bf2f(*(const unsigned short*)(P + row * 256 + ((j * 2) ^ ((row & 7) << 4))));
        }
#pragma unroll
        for (int k = 0; k < 8; ++k) {
          const int nd = sl[r0 + b8 * 8 + k];
          if (nd != curn) {
            float* dst = f2sum + (size_t)curn * HD + j;
            if (inside) *dst = acc; else atomicAdd(dst, acc);
            inside = true; acc = 0.f; curn = nd;
          }
          acc += vals[k];
        }
      }
      atomicAdd(f2sum + (size_t)curn * HD + j, acc);
    }
    // restage next tile into A last
    if (tn < NTILE) {
      cvt_write256(gv, A + sr * 256, q, sr);
      if (tid < 128) { segL[cur ^ 1][tid] = sgn; smrow[cur ^ 1][tid] = smn; }
    }
    cur ^= 1;
  }
}

// ---------------- node GEMMs (MFMA, K=256 two-half), persistent ----------------
template <bool L2>
__global__ __launch_bounds__(512) void k_ngemm(
    const float* __restrict__ P1, const float* __restrict__ P2,
    const float* __restrict__ rcv,
    const float* __restrict__ WA, const float* __restrict__ WB,
    const float* __restrict__ stats_in,
    const float* __restrict__ gp, const float* __restrict__ bp,
    float* __restrict__ out, float* __restrict__ so) {
  constexpr int KH = L2 ? HD : FD;
  __shared__ char lds[131072];   // A @0 (64KB, 512B rows), B @65536 (64KB)
  __shared__ float sred[16];
  const int tid = threadIdx.x;
  float a1 = 1.f, c1 = 0.f;
  if (L2) {
    const float m = stats_in[0] * (1.f / ((float)NN * (float)HD));
    const float var = stats_in[1] * (1.f / ((float)NN * (float)HD)) - m * m;
    const float inv = rsqrtf(var + EPSF);
    a1 = gp[0] * inv; c1 = bp[0] - gp[0] * m * inv;
  }
  const int sr = tid >> 2, q = tid & 3;
  const bool half2 = (q >= 2);
  const int cbase = (q & 1) * 64;
  // stage B once (rows = output dims, halves = WA/WB)
  {
    const float* src = (half2 ? WB : WA) + (size_t)sr * KH;
    float v[64];
#pragma unroll
    for (int i4 = 0; i4 < 16; ++i4) {
      const int c = cbase + i4 * 4;
      float4 tv = make_float4(0.f, 0.f, 0.f, 0.f);
      if (c < KH) tv = *(const float4*)(src + c);
      v[i4 * 4 + 0] = tv.x; v[i4 * 4 + 1] = tv.y; v[i4 * 4 + 2] = tv.z; v[i4 * 4 + 3] = tv.w;
    }
    char* db = lds + 65536 + sr * 512;
#pragma unroll
    for (int h = 0; h < 8; ++h) {
      short8 s8;
#pragma unroll
      for (int e = 0; e < 8; ++e) s8[e] = (short)f2bf(v[h * 8 + e]);
      *(short8*)(db + ((q * 128 + h * 16) ^ ((sr & 7) << 4))) = s8;
    }
  }
  const int w = tid >> 6, l = tid & 63, lr = l & 15, lh = l >> 4;
  float ls = 0.f, lsq = 0.f;
  for (int bt = blockIdx.x; bt < NT_NODE; bt += gridDim.x) {
    __syncthreads();  // B visible (first iter); prev iter's A reads done
    const size_t rg = (size_t)bt * 128 + sr;
    {
      const float* src = (half2 ? P2 : P1) + rg * KH;
      const float sc = half2 ? ((rg < NN) ? rcv[rg] : 0.f) : 1.f;
      float v[64];
#pragma unroll
      for (int i4 = 0; i4 < 16; ++i4) {
        const int c = cbase + i4 * 4;
        float4 tv = make_float4(0.f, 0.f, 0.f, 0.f);
        if (rg < NN && c < KH) tv = *(const float4*)(src + c);
        float e0 = tv.x, e1 = tv.y, e2 = tv.z, e3 = tv.w;
        if (half2) { e0 *= sc; e1 *= sc; e2 *= sc; e3 *= sc; }
        else if (L2 && rg < NN) {  // gate on rg<NN: padded rows must stay 0
          e0 = fmaxf(fmaf(a1, e0, c1), 0.f); e1 = fmaxf(fmaf(a1, e1, c1), 0.f);
          e2 = fmaxf(fmaf(a1, e2, c1), 0.f); e3 = fmaxf(fmaf(a1, e3, c1), 0.f);
        }
        v[i4 * 4 + 0] = e0; v[i4 * 4 + 1] = e1; v[i4 * 4 + 2] = e2; v[i4 * 4 + 3] = e3;
      }
      char* db = lds + sr * 512;
#pragma unroll
      for (int h = 0; h < 8; ++h) {
        short8 s8;
#pragma unroll
        for (int e = 0; e < 8; ++e) s8[e] = (short)f2bf(v[h * 8 + e]);
        *(short8*)(db + ((q * 128 + h * 16) ^ ((sr & 7) << 4))) = s8;
      }
    }
    __syncthreads();
    short8 af[8];
    const int arow = w * 16 + lr;
#pragma unroll
    for (int kk = 0; kk < 8; ++kk)
      af[kk] = *(const short8*)(lds + arow * 512 + ((lh * 16 + kk * 64) ^ ((arow & 7) << 4)));
    const char* B = lds + 65536;
#pragma unroll
    for (int nt = 0; nt < 8; ++nt) {
      f32x4 acc = {0.f, 0.f, 0.f, 0.f};
#pragma unroll
      for (int kk = 0; kk < 8; ++kk) {
        const int n = nt * 16 + lr;
        const short8 bfg = *(const short8*)(B + n * 512 + ((lh * 16 + kk * 64) ^ ((n & 7) << 4)));
        acc = __builtin_amdgcn_mfma_f32_16x16x32_bf16(af[kk], bfg, acc, 0, 0, 0);
      }
      const int col = nt * 16 + lr;
#pragma unroll
      for (int r = 0; r < 4; ++r) {
        const float val = acc[r];
        const size_t rg2 = (size_t)bt * 128 + w * 16 + lh * 4 + r;
        if (rg2 < NN) out[rg2 * HD + col] = val;
        ls += val;
        lsq = fmaf(val, val, lsq);
      }
    }
  }
#pragma unroll
  for (int off = 32; off > 0; off >>= 1) { ls += __shfl_down(ls, off); lsq += __shfl_down(lsq, off); }
  if ((tid & 63) == 0) { sred[(tid >> 6) * 2] = ls; sred[(tid >> 6) * 2 + 1] = lsq; }
  __syncthreads();
  if (tid == 0) {
    float S = 0.f, Q = 0.f;
#pragma unroll
    for (int i = 0; i < 8; ++i) { S += sred[i * 2]; Q += sred[i * 2 + 1]; }
    atomicAdd(&so[0], S);
    atomicAdd(&so[1], Q);
  }
}

// ---------------- classifier: out = bnrelu(h2) @ Wc^T + bc ----------------
__global__ __launch_bounds__(512) void k_cls(
    const float* __restrict__ h2, const float* __restrict__ Wc,
    const float* __restrict__ bc, const float* __restrict__ stats,
    const float* __restrict__ gp, const float* __restrict__ bp,
    float* __restrict__ out) {
  __shared__ char lds[45056];
  const int tid = threadIdx.x;
  const float m = stats[0] * (1.f / ((float)NN * (float)HD));
  const float var = stats[1] * (1.f / ((float)NN * (float)HD)) - m * m;
  const float inv = rsqrtf(var + EPSF);
  const float g = gp[0], bb = bp[0];
  const float a2 = g * inv, c2 = bb - g * m * inv;
  const int sr = tid >> 2, q = tid & 3;
  const size_t rg = (size_t)blockIdx.x * 128 + sr;
  {
    float4 gv[8];
#pragma unroll
    for (int i4 = 0; i4 < 8; ++i4) {
      const int c = q * 32 + i4 * 4;
      float4 t = (rg < NN) ? *(const float4*)(h2 + rg * HD + c) : make_float4(0.f, 0.f, 0.f, 0.f);
      t.x = fmaxf(fmaf(a2, t.x, c2), 0.f); t.y = fmaxf(fmaf(a2, t.y, c2), 0.f);
      t.z = fmaxf(fmaf(a2, t.z, c2), 0.f); t.w = fmaxf(fmaf(a2, t.w, c2), 0.f);
      gv[i4] = t;
    }
    cvt_write256(gv, lds + sr * 256, q, sr);
  }
  if (tid < 192) {
    const int bn = tid >> 2, bq = tid & 3;
    float4 gv[8];
#pragma unroll
    for (int i4 = 0; i4 < 8; ++i4) {
      const int c = bq * 32 + i4 * 4;
      gv[i4] = (bn < CD) ? *(const float4*)(Wc + (size_t)bn * HD + c) : make_float4(0.f, 0.f, 0.f, 0.f);
    }
    cvt_write256(gv, lds + 32768 + bn * 256, bq, bn);
  }
  __syncthreads();
  const int w = tid >> 6, l = tid & 63, lr = l & 15, lh = l >> 4;
  short8 af[4];
  const int arow = w * 16 + lr;
#pragma unroll
  for (int kk = 0; kk < 4; ++kk)
    af[kk] = *(const short8*)(lds + arow * 256 + ((lh * 16 + kk * 64) ^ ((arow & 7) << 4)));
#pragma unroll
  for (int nt = 0; nt < 3; ++nt) {
    f32x4 acc = {0.f, 0.f, 0.f, 0.f};
#pragma unroll
    for (int kk = 0; kk < 4; ++kk) {
      const int n = nt * 16 + lr;
      const short8 bfg = *(const short8*)(lds + 32768 + n * 256 + ((lh * 16 + kk * 64) ^ ((n & 7) << 4)));
      acc = __builtin_amdgcn_mfma_f32_16x16x32_bf16(af[kk], bfg, acc, 0, 0, 0);
    }
    const int col = nt * 16 + lr;
    if (col < CD) {
      const float bias = bc[col];
#pragma unroll
      for (int r = 0; r < 4; ++r) {
        const size_t rg2 = (size_t)blockIdx.x * 128 + w * 16 + lh * 4 + r;
        if (rg2 < NN) out[rg2 * CD + col] = acc[r] + bias;
      }
    }
  }
}

extern "C" void kernel_launch(void* const* d_in, const int* in_sizes, int n_in,
                              void* d_out, int out_size, void* d_ws, size_t ws_size,
                              hipStream_t stream) {
  const float* x   = (const float*)d_in[0];
  const float* nbr = (const float*)d_in[1];
  const int*   seg = (const int*)d_in[2];
  const float* W1x = (const float*)d_in[3];
  const float* W1n = (const float*)d_in[4];
  const float* g1  = (const float*)d_in[5];
  const float* b1  = (const float*)d_in[6];
  const float* W2x = (const float*)d_in[7];
  const float* W2n = (const float*)d_in[8];
  const float* g2  = (const float*)d_in[9];
  const float* b2  = (const float*)d_in[10];
  const float* Wc  = (const float*)d_in[11];
  const float* bc  = (const float*)d_in[12];
  float* out = (float*)d_out;

  char* p = (char*)d_ws;
  auto alloc = [&](size_t bytes) {
    char* q = p;
    p += (bytes + 255) & ~(size_t)255;
    return q;
  };
  int*    rp    = (int*)   alloc(sizeof(int) * (NN + 1));
  float*  fsum  = (float*) alloc(sizeof(float) * (size_t)NN * FD);
  float*  f2sum = (float*) alloc(sizeof(float) * (size_t)NN * HD);
  float*  hpre  = (float*) alloc(sizeof(float) * (size_t)NN * HD);
  float*  h2    = (float*) alloc(sizeof(float) * (size_t)NN * HD);
  float*  stats = (float*) alloc(sizeof(float) * 4);
  float*  es    = (float*) alloc(sizeof(float) * (size_t)NE);
  float*  eq    = (float*) alloc(sizeof(float) * (size_t)NE);
  float2* smi   = (float2*)alloc(sizeof(float2) * (size_t)NN);
  float*  rcv   = (float*) alloc(sizeof(float) * (size_t)NN);

  hipMemsetAsync(stats, 0, sizeof(float) * 4, stream);
  hipMemsetAsync(fsum, 0, sizeof(float) * (size_t)NN * FD, stream);
  hipMemsetAsync(f2sum, 0, sizeof(float) * (size_t)NN * HD, stream);

  k_rowptr<<<(NN + 256) / 256, 256, 0, stream>>>(seg, rp);
  k_gemm1<<<GRID_EDGE, 512, 0, stream>>>(nbr, seg, W1x, es, eq, fsum);
  k_nodestats<<<(NN + 255) / 256, 256, 0, stream>>>(rp, es, eq, smi, rcv);
  k_fuse2<<<GRID_EDGE, 512, 0, stream>>>(nbr, seg, W1x, smi, g1, b1, f2sum);
  k_ngemm<false><<<256, 512, 0, stream>>>(x, fsum, rcv, W1x, W1n, stats, g1, b1, hpre, stats);
  k_ngemm<true><<<256, 512, 0, stream>>>(hpre, f2sum, rcv, W2x, W2n, stats, g1, b1, h2, stats + 2);
  k_cls<<<NT_NODE, 512, 0, stream>>>(h2, Wc, bc, stats + 2, g2, b2, out);
}

// Round 9
// 425.881 us; speedup vs baseline: 1.8278x; 1.0498x over previous
//
#include <hip/hip_runtime.h>
#include <hip/hip_bf16.h>
#include <math.h>

#define NN 50000
#define NE 800000
#define FD 100
#define HD 128
#define CD 40
#define EPSF 1e-5f
#define NTILE 6250    // NE / 128 exactly
#define GRID_EDGE 512 // 2 blocks/CU
#define NT_NODE 391   // ceil(NN/128)

typedef __attribute__((ext_vector_type(8))) short short8;
typedef __attribute__((ext_vector_type(4))) float f32x4;

__device__ __forceinline__ unsigned short f2bf(float x) {
  union { __hip_bfloat16 h; unsigned short u; } cv;
  cv.h = __float2bfloat16(x);
  return cv.u;
}
__device__ __forceinline__ float bf2f(unsigned short b) {
  return __uint_as_float(((unsigned)b) << 16);
}

// Barrier that only waits on LDS (lgkm) traffic: does NOT drain outstanding
// global loads/stores/atomics (vmcnt) like __syncthreads() does.
__device__ __forceinline__ void bar_lds() {
  asm volatile("s_waitcnt lgkmcnt(0)\n\ts_barrier" ::: "memory");
}

// row_ptr[i] = first edge index with seg_ids >= i
__global__ void k_rowptr(const int* __restrict__ seg, int* __restrict__ rp) {
  int i = blockIdx.x * blockDim.x + threadIdx.x;
  if (i > NN) return;
  int lo = 0, hi = NE;
  while (lo < hi) { int mid = (lo + hi) >> 1; if (seg[mid] < i) lo = mid + 1; else hi = mid; }
  rp[i] = lo;
}

// convert 32 f32 (in 8 float4) -> 4 swizzled short8 LDS writes (row stride 256B)
__device__ __forceinline__ void cvt_write256(const float4* gv, char* rowbase, int q, int sr) {
  const float* vf = (const float*)gv;
#pragma unroll
  for (int h = 0; h < 4; ++h) {
    short8 s;
#pragma unroll
    for (int e = 0; e < 8; ++e) s[e] = (short)f2bf(vf[h * 8 + e]);
    *(short8*)(rowbase + ((q * 64 + h * 16) ^ ((sr & 7) << 4))) = s;
  }
}

// load one 128-row x FD f32 tile row-quarter into gv (masked to FD cols)
__device__ __forceinline__ void load_quarters(const float* src, int q, float4* gv) {
#pragma unroll
  for (int i4 = 0; i4 < 8; ++i4) {
    const int c = q * 32 + i4 * 4;
    gv[i4] = (c < FD) ? *(const float4*)(src + c) : make_float4(0.f, 0.f, 0.f, 0.f);
  }
}

// ---------------- pass 1: MFMA edge GEMM -> Ssum/Qsum (node BN stats) + fsum ----------
// LDS: B (32KB resident) + A (32KB single buffer) = 64KB -> 2 blocks/CU.
// Per tile: [bar] af+MFMA+stats-atomics+scan (all read A) [bar] restage A.
__global__ __launch_bounds__(512, 4) void k_gemm1(
    const float* __restrict__ nbr, const int* __restrict__ seg,
    const float* __restrict__ W1x,
    float* __restrict__ Ssum, float* __restrict__ Qsum, float* __restrict__ fsum) {
  __shared__ char lds[65536];   // [0,32K)=B  [32K,64K)=A
  __shared__ int segL[128];
  char* A = lds + 32768;
  const int tid = threadIdx.x;
  const int sr = tid >> 2, q = tid & 3;
  const int w = tid >> 6, l = tid & 63, lr = l & 15, lh = l >> 4;

  // stage B = W1x (resident) and first A tile; loop-top barrier makes visible
  {
    float4 gv[8];
    load_quarters(W1x + (size_t)sr * FD, q, gv);
    cvt_write256(gv, lds + sr * 256, q, sr);
    load_quarters(nbr + (size_t)(blockIdx.x * 128 + sr) * FD, q, gv);
    cvt_write256(gv, A + sr * 256, q, sr);
    if (tid < 128) segL[tid] = seg[blockIdx.x * 128 + tid];
  }
  for (int t = blockIdx.x; t < NTILE; t += GRID_EDGE) {
    const int tn = t + GRID_EDGE;
    float4 gv[8];
    int sgn = 0;
    if (tn < NTILE) {  // issue next tile's global loads early
      load_quarters(nbr + (size_t)(tn * 128 + sr) * FD, q, gv);
      if (tid < 128) sgn = seg[tn * 128 + tid];
    }
    bar_lds();  // A + segL staged & visible
    short8 af[4];
    const int arow = w * 16 + lr;
#pragma unroll
    for (int kk = 0; kk < 4; ++kk)
      af[kk] = *(const short8*)(A + arow * 256 + ((lh * 16 + kk * 64) ^ ((arow & 7) << 4)));

    float rs[4] = {0.f, 0.f, 0.f, 0.f}, rq[4] = {0.f, 0.f, 0.f, 0.f};
#pragma unroll
    for (int nt = 0; nt < 8; ++nt) {
      f32x4 acc = {0.f, 0.f, 0.f, 0.f};
#pragma unroll
      for (int kk = 0; kk < 4; ++kk) {
        const int n = nt * 16 + lr;
        const short8 bfg = *(const short8*)(lds + n * 256 + ((lh * 16 + kk * 64) ^ ((n & 7) << 4)));
        acc = __builtin_amdgcn_mfma_f32_16x16x32_bf16(af[kk], bfg, acc, 0, 0, 0);
      }
#pragma unroll
      for (int r = 0; r < 4; ++r) {
        const float val = acc[r];
        rs[r] += val;
        rq[r] = fmaf(val, val, rq[r]);
      }
    }
    // per-row sum/sumsq -> lr==0 lanes -> run-compressed atomics into Ssum/Qsum
    float sv[4], qv[4];
#pragma unroll
    for (int r = 0; r < 4; ++r) {
      float a = rs[r], b = rq[r];
#pragma unroll
      for (int off = 1; off < 16; off <<= 1) { a += __shfl_xor(a, off); b += __shfl_xor(b, off); }
      sv[r] = a; qv[r] = b;
    }
    if (lr == 0) {
      const int R = w * 16 + lh * 4;
      const int4 nid = *(const int4*)&segL[R];
      float sa = sv[0], qa = qv[0];
      int curn = nid.x;
      if (nid.y != curn) { atomicAdd(&Ssum[curn], sa); atomicAdd(&Qsum[curn], qa); sa = 0.f; qa = 0.f; curn = nid.y; }
      sa += sv[1]; qa += qv[1];
      if (nid.z != curn) { atomicAdd(&Ssum[curn], sa); atomicAdd(&Qsum[curn], qa); sa = 0.f; qa = 0.f; curn = nid.z; }
      sa += sv[2]; qa += qv[2];
      if (nid.w != curn) { atomicAdd(&Ssum[curn], sa); atomicAdd(&Qsum[curn], qa); sa = 0.f; qa = 0.f; curn = nid.w; }
      sa += sv[3]; qa += qv[3];
      atomicAdd(&Ssum[curn], sa); atomicAdd(&Qsum[curn], qa);
    }
    // fsum scan of bf16 A-tile: register-batched, quarter-split segmented sum
    {
      const int qq = tid >> 7, j = tid & 127;
      if (j < FD) {
        const int r0 = qq * 32;
        int curn = segL[r0];
        float acc = 0.f;
        bool inside = false;
#pragma unroll
        for (int b8 = 0; b8 < 4; ++b8) {
          float vals[8];
#pragma unroll
          for (int k = 0; k < 8; ++k) {
            const int row = r0 + b8 * 8 + k;
            vals[k] = bf2f(*(const unsigned short*)(A + row * 256 + ((j * 2) ^ ((row & 7) << 4))));
          }
#pragma unroll
          for (int k = 0; k < 8; ++k) {
            const int nd = segL[r0 + b8 * 8 + k];
            if (nd != curn) {
              float* dst = fsum + (size_t)curn * FD + j;
              if (inside) *dst = acc; else atomicAdd(dst, acc);
              inside = true; acc = 0.f; curn = nd;
            }
            acc += vals[k];
          }
        }
        atomicAdd(fsum + (size_t)curn * FD + j, acc);
      }
    }
    bar_lds();  // all A/segL reads complete
    if (tn < NTILE) {  // restage A for next tile
      cvt_write256(gv, A + sr * 256, q, sr);
      if (tid < 128) segL[tid] = sgn;
    }
  }
}

// per-node BN stats (O(1)/node now)
__global__ void k_nodestats(const int* __restrict__ rp, const float* __restrict__ Ssum,
                            const float* __restrict__ Qsum, float2* __restrict__ smi,
                            float* __restrict__ rcv) {
  const int i = blockIdx.x * blockDim.x + threadIdx.x;
  if (i >= NN) return;
  const int cnt = rp[i + 1] - rp[i];
  const float ne = fmaxf((float)cnt * (float)HD, 1.f);
  const float sm = Ssum[i] / ne;
  const float var = Qsum[i] / ne - sm * sm;
  smi[i] = make_float2(sm, rsqrtf(var + EPSF));
  rcv[i] = 1.f / (float)(cnt > 0 ? cnt : 1);
}

// ---------------- pass 2: recompute MFMA, BN+ReLU, scan -> f2sum ----------------
// LDS: B (32KB) + A (32KB, reused as P after af consumed) = 64KB -> 2 blocks/CU.
__global__ __launch_bounds__(512, 4) void k_fuse2(
    const float* __restrict__ nbr, const int* __restrict__ seg,
    const float* __restrict__ W1x, const float2* __restrict__ smi,
    const float* __restrict__ g1p, const float* __restrict__ b1p,
    float* __restrict__ f2sum) {
  __shared__ char lds[65536];   // [0,32K)=B  [32K,64K)=A (then P in place)
  __shared__ int segL[128];
  __shared__ float2 smrow[128];
  char* A = lds + 32768;
  const int tid = threadIdx.x;
  const int sr = tid >> 2, q = tid & 3;
  const int w = tid >> 6, l = tid & 63, lr = l & 15, lh = l >> 4;
  const float g1 = g1p[0], b1 = b1p[0];

  {
    float4 gv[8];
    load_quarters(W1x + (size_t)sr * FD, q, gv);
    cvt_write256(gv, lds + sr * 256, q, sr);
    load_quarters(nbr + (size_t)(blockIdx.x * 128 + sr) * FD, q, gv);
    cvt_write256(gv, A + sr * 256, q, sr);
    if (tid < 128) {
      const int nd = seg[blockIdx.x * 128 + tid];
      segL[tid] = nd;
      smrow[tid] = smi[nd];
    }
  }
  for (int t = blockIdx.x; t < NTILE; t += GRID_EDGE) {
    const int tn = t + GRID_EDGE;
    float4 gv[8];
    int sgn = 0;
    float2 smn = make_float2(0.f, 0.f);
    if (tn < NTILE) {
      load_quarters(nbr + (size_t)(tn * 128 + sr) * FD, q, gv);
      if (tid < 128) { sgn = seg[tn * 128 + tid]; smn = smi[sgn]; }
    }
    bar_lds();  // A + segL/smrow staged & visible
    short8 af[4];
    const int arow = w * 16 + lr;
#pragma unroll
    for (int kk = 0; kk < 4; ++kk)
      af[kk] = *(const short8*)(A + arow * 256 + ((lh * 16 + kk * 64) ^ ((arow & 7) << 4)));
    float2 mi[4];
#pragma unroll
    for (int r = 0; r < 4; ++r) mi[r] = smrow[w * 16 + lh * 4 + r];
    bar_lds();  // every thread's af reads done -> safe to overwrite A with P
#pragma unroll
    for (int nt = 0; nt < 8; ++nt) {
      f32x4 acc = {0.f, 0.f, 0.f, 0.f};
#pragma unroll
      for (int kk = 0; kk < 4; ++kk) {
        const int n = nt * 16 + lr;
        const short8 bfg = *(const short8*)(lds + n * 256 + ((lh * 16 + kk * 64) ^ ((n & 7) << 4)));
        acc = __builtin_amdgcn_mfma_f32_16x16x32_bf16(af[kk], bfg, acc, 0, 0, 0);
      }
      const int col = nt * 16 + lr;
#pragma unroll
      for (int r = 0; r < 4; ++r) {
        const int row = w * 16 + lh * 4 + r;
        const float v = fmaxf(fmaf(g1, (acc[r] - mi[r].x) * mi[r].y, b1), 0.f);
        *(unsigned short*)(A + row * 256 + ((col * 2) ^ ((row & 7) << 4))) = f2bf(v);
      }
    }
    bar_lds();  // P complete
    // f2sum scan of P: register-batched, quarter-split segmented sum
    {
      const int qq = tid >> 7, j = tid & 127;
      const int r0 = qq * 32;
      int curn = segL[r0];
      float acc = 0.f;
      bool inside = false;
#pragma unroll
      for (int b8 = 0; b8 < 4; ++b8) {
        float vals[8];
#pragma unroll
        for (int k = 0; k < 8; ++k) {
          const int row = r0 + b8 * 8 + k;
          vals[k] = bf2f(*(const unsigned short*)(A + row * 256 + ((j * 2) ^ ((row & 7) << 4))));
        }
#pragma unroll
        for (int k = 0; k < 8; ++k) {
          const int nd = segL[r0 + b8 * 8 + k];
          if (nd != curn) {
            float* dst = f2sum + (size_t)curn * HD + j;
            if (inside) *dst = acc; else atomicAdd(dst, acc);
            inside = true; acc = 0.f; curn = nd;
          }
          acc += vals[k];
        }
      }
      atomicAdd(f2sum + (size_t)curn * HD + j, acc);
    }
    bar_lds();  // scan reads done -> A free for restage
    if (tn < NTILE) {
      cvt_write256(gv, A + sr * 256, q, sr);
      if (tid < 128) { segL[tid] = sgn; smrow[tid] = smn; }
    }
  }
}

// ---------------- node GEMMs (MFMA, K=256 two-half), persistent ----------------
template <bool L2>
__global__ __launch_bounds__(512) void k_ngemm(
    const float* __restrict__ P1, const float* __restrict__ P2,
    const float* __restrict__ rcv,
    const float* __restrict__ WA, const float* __restrict__ WB,
    const float* __restrict__ stats_in,
    const float* __restrict__ gp, const float* __restrict__ bp,
    float* __restrict__ out, float* __restrict__ so) {
  constexpr int KH = L2 ? HD : FD;
  __shared__ char lds[131072];   // A @0 (64KB, 512B rows), B @65536 (64KB)
  __shared__ float sred[16];
  const int tid = threadIdx.x;
  float a1 = 1.f, c1 = 0.f;
  if (L2) {
    const float m = stats_in[0] * (1.f / ((float)NN * (float)HD));
    const float var = stats_in[1] * (1.f / ((float)NN * (float)HD)) - m * m;
    const float inv = rsqrtf(var + EPSF);
    a1 = gp[0] * inv; c1 = bp[0] - gp[0] * m * inv;
  }
  const int sr = tid >> 2, q = tid & 3;
  const bool half2 = (q >= 2);
  const int cbase = (q & 1) * 64;
  {
    const float* src = (half2 ? WB : WA) + (size_t)sr * KH;
    float v[64];
#pragma unroll
    for (int i4 = 0; i4 < 16; ++i4) {
      const int c = cbase + i4 * 4;
      float4 tv = make_float4(0.f, 0.f, 0.f, 0.f);
      if (c < KH) tv = *(const float4*)(src + c);
      v[i4 * 4 + 0] = tv.x; v[i4 * 4 + 1] = tv.y; v[i4 * 4 + 2] = tv.z; v[i4 * 4 + 3] = tv.w;
    }
    char* db = lds + 65536 + sr * 512;
#pragma unroll
    for (int h = 0; h < 8; ++h) {
      short8 s8;
#pragma unroll
      for (int e = 0; e < 8; ++e) s8[e] = (short)f2bf(v[h * 8 + e]);
      *(short8*)(db + ((q * 128 + h * 16) ^ ((sr & 7) << 4))) = s8;
    }
  }
  const int w = tid >> 6, l = tid & 63, lr = l & 15, lh = l >> 4;
  float ls = 0.f, lsq = 0.f;
  for (int bt = blockIdx.x; bt < NT_NODE; bt += gridDim.x) {
    __syncthreads();  // B visible (first iter); prev iter's A reads done
    const size_t rg = (size_t)bt * 128 + sr;
    {
      const float* src = (half2 ? P2 : P1) + rg * KH;
      const float sc = half2 ? ((rg < NN) ? rcv[rg] : 0.f) : 1.f;
      float v[64];
#pragma unroll
      for (int i4 = 0; i4 < 16; ++i4) {
        const int c = cbase + i4 * 4;
        float4 tv = make_float4(0.f, 0.f, 0.f, 0.f);
        if (rg < NN && c < KH) tv = *(const float4*)(src + c);
        float e0 = tv.x, e1 = tv.y, e2 = tv.z, e3 = tv.w;
        if (half2) { e0 *= sc; e1 *= sc; e2 *= sc; e3 *= sc; }
        else if (L2 && rg < NN) {  // padded rows must stay 0
          e0 = fmaxf(fmaf(a1, e0, c1), 0.f); e1 = fmaxf(fmaf(a1, e1, c1), 0.f);
          e2 = fmaxf(fmaf(a1, e2, c1), 0.f); e3 = fmaxf(fmaf(a1, e3, c1), 0.f);
        }
        v[i4 * 4 + 0] = e0; v[i4 * 4 + 1] = e1; v[i4 * 4 + 2] = e2; v[i4 * 4 + 3] = e3;
      }
      char* db = lds + sr * 512;
#pragma unroll
      for (int h = 0; h < 8; ++h) {
        short8 s8;
#pragma unroll
        for (int e = 0; e < 8; ++e) s8[e] = (short)f2bf(v[h * 8 + e]);
        *(short8*)(db + ((q * 128 + h * 16) ^ ((sr & 7) << 4))) = s8;
      }
    }
    __syncthreads();
    short8 af[8];
    const int arow = w * 16 + lr;
#pragma unroll
    for (int kk = 0; kk < 8; ++kk)
      af[kk] = *(const short8*)(lds + arow * 512 + ((lh * 16 + kk * 64) ^ ((arow & 7) << 4)));
    const char* B = lds + 65536;
#pragma unroll
    for (int nt = 0; nt < 8; ++nt) {
      f32x4 acc = {0.f, 0.f, 0.f, 0.f};
#pragma unroll
      for (int kk = 0; kk < 8; ++kk) {
        const int n = nt * 16 + lr;
        const short8 bfg = *(const short8*)(B + n * 512 + ((lh * 16 + kk * 64) ^ ((n & 7) << 4)));
        acc = __builtin_amdgcn_mfma_f32_16x16x32_bf16(af[kk], bfg, acc, 0, 0, 0);
      }
      const int col = nt * 16 + lr;
#pragma unroll
      for (int r = 0; r < 4; ++r) {
        const float val = acc[r];
        const size_t rg2 = (size_t)bt * 128 + w * 16 + lh * 4 + r;
        if (rg2 < NN) out[rg2 * HD + col] = val;
        ls += val;
        lsq = fmaf(val, val, lsq);
      }
    }
  }
#pragma unroll
  for (int off = 32; off > 0; off >>= 1) { ls += __shfl_down(ls, off); lsq += __shfl_down(lsq, off); }
  if ((tid & 63) == 0) { sred[(tid >> 6) * 2] = ls; sred[(tid >> 6) * 2 + 1] = lsq; }
  __syncthreads();
  if (tid == 0) {
    float S = 0.f, Q = 0.f;
#pragma unroll
    for (int i = 0; i < 8; ++i) { S += sred[i * 2]; Q += sred[i * 2 + 1]; }
    atomicAdd(&so[0], S);
    atomicAdd(&so[1], Q);
  }
}

// ---------------- classifier: out = bnrelu(h2) @ Wc^T + bc ----------------
__global__ __launch_bounds__(512) void k_cls(
    const float* __restrict__ h2, const float* __restrict__ Wc,
    const float* __restrict__ bc, const float* __restrict__ stats,
    const float* __restrict__ gp, const float* __restrict__ bp,
    float* __restrict__ out) {
  __shared__ char lds[45056];
  const int tid = threadIdx.x;
  const float m = stats[0] * (1.f / ((float)NN * (float)HD));
  const float var = stats[1] * (1.f / ((float)NN * (float)HD)) - m * m;
  const float inv = rsqrtf(var + EPSF);
  const float g = gp[0], bb = bp[0];
  const float a2 = g * inv, c2 = bb - g * m * inv;
  const int sr = tid >> 2, q = tid & 3;
  const size_t rg = (size_t)blockIdx.x * 128 + sr;
  {
    float4 gv[8];
#pragma unroll
    for (int i4 = 0; i4 < 8; ++i4) {
      const int c = q * 32 + i4 * 4;
      float4 t = (rg < NN) ? *(const float4*)(h2 + rg * HD + c) : make_float4(0.f, 0.f, 0.f, 0.f);
      t.x = fmaxf(fmaf(a2, t.x, c2), 0.f); t.y = fmaxf(fmaf(a2, t.y, c2), 0.f);
      t.z = fmaxf(fmaf(a2, t.z, c2), 0.f); t.w = fmaxf(fmaf(a2, t.w, c2), 0.f);
      gv[i4] = t;
    }
    cvt_write256(gv, lds + sr * 256, q, sr);
  }
  if (tid < 192) {
    const int bn = tid >> 2, bq = tid & 3;
    float4 gv[8];
#pragma unroll
    for (int i4 = 0; i4 < 8; ++i4) {
      const int c = bq * 32 + i4 * 4;
      gv[i4] = (bn < CD) ? *(const float4*)(Wc + (size_t)bn * HD + c) : make_float4(0.f, 0.f, 0.f, 0.f);
    }
    cvt_write256(gv, lds + 32768 + bn * 256, bq, bn);
  }
  __syncthreads();
  const int w = tid >> 6, l = tid & 63, lr = l & 15, lh = l >> 4;
  short8 af[4];
  const int arow = w * 16 + lr;
#pragma unroll
  for (int kk = 0; kk < 4; ++kk)
    af[kk] = *(const short8*)(lds + arow * 256 + ((lh * 16 + kk * 64) ^ ((arow & 7) << 4)));
#pragma unroll
  for (int nt = 0; nt < 3; ++nt) {
    f32x4 acc = {0.f, 0.f, 0.f, 0.f};
#pragma unroll
    for (int kk = 0; kk < 4; ++kk) {
      const int n = nt * 16 + lr;
      const short8 bfg = *(const short8*)(lds + 32768 + n * 256 + ((lh * 16 + kk * 64) ^ ((n & 7) << 4)));
      acc = __builtin_amdgcn_mfma_f32_16x16x32_bf16(af[kk], bfg, acc, 0, 0, 0);
    }
    const int col = nt * 16 + lr;
    if (col < CD) {
      const float bias = bc[col];
#pragma unroll
      for (int r = 0; r < 4; ++r) {
        const size_t rg2 = (size_t)blockIdx.x * 128 + w * 16 + lh * 4 + r;
        if (rg2 < NN) out[rg2 * CD + col] = acc[r] + bias;
      }
    }
  }
}

extern "C" void kernel_launch(void* const* d_in, const int* in_sizes, int n_in,
                              void* d_out, int out_size, void* d_ws, size_t ws_size,
                              hipStream_t stream) {
  const float* x   = (const float*)d_in[0];
  const float* nbr = (const float*)d_in[1];
  const int*   seg = (const int*)d_in[2];
  const float* W1x = (const float*)d_in[3];
  const float* W1n = (const float*)d_in[4];
  const float* g1  = (const float*)d_in[5];
  const float* b1  = (const float*)d_in[6];
  const float* W2x = (const float*)d_in[7];
  const float* W2n = (const float*)d_in[8];
  const float* g2  = (const float*)d_in[9];
  const float* b2  = (const float*)d_in[10];
  const float* Wc  = (const float*)d_in[11];
  const float* bc  = (const float*)d_in[12];
  float* out = (float*)d_out;

  char* p = (char*)d_ws;
  auto alloc = [&](size_t bytes) {
    char* q = p;
    p += (bytes + 255) & ~(size_t)255;
    return q;
  };
  int*    rp    = (int*)   alloc(sizeof(int) * (NN + 1));
  float*  fsum  = (float*) alloc(sizeof(float) * (size_t)NN * FD);
  float*  f2sum = (float*) alloc(sizeof(float) * (size_t)NN * HD);
  float*  hpre  = (float*) alloc(sizeof(float) * (size_t)NN * HD);
  float*  h2    = (float*) alloc(sizeof(float) * (size_t)NN * HD);
  float*  stats = (float*) alloc(sizeof(float) * 4);
  float*  Ssum  = (float*) alloc(sizeof(float) * (size_t)NN);
  float*  Qsum  = (float*) alloc(sizeof(float) * (size_t)NN);
  float2* smi   = (float2*)alloc(sizeof(float2) * (size_t)NN);
  float*  rcv   = (float*) alloc(sizeof(float) * (size_t)NN);

  hipMemsetAsync(stats, 0, sizeof(float) * 4, stream);
  hipMemsetAsync(fsum, 0, sizeof(float) * (size_t)NN * FD, stream);
  hipMemsetAsync(f2sum, 0, sizeof(float) * (size_t)NN * HD, stream);
  hipMemsetAsync(Ssum, 0, sizeof(float) * (size_t)NN, stream);
  hipMemsetAsync(Qsum, 0, sizeof(float) * (size_t)NN, stream);

  k_rowptr<<<(NN + 256) / 256, 256, 0, stream>>>(seg, rp);
  k_gemm1<<<GRID_EDGE, 512, 0, stream>>>(nbr, seg, W1x, Ssum, Qsum, fsum);
  k_nodestats<<<(NN + 255) / 256, 256, 0, stream>>>(rp, Ssum, Qsum, smi, rcv);
  k_fuse2<<<GRID_EDGE, 512, 0, stream>>>(nbr, seg, W1x, smi, g1, b1, f2sum);
  k_ngemm<false><<<256, 512, 0, stream>>>(x, fsum, rcv, W1x, W1n, stats, g1, b1, hpre, stats);
  k_ngemm<true><<<256, 512, 0, stream>>>(hpre, f2sum, rcv, W2x, W2n, stats, g1, b1, h2, stats + 2);
  k_cls<<<NT_NODE, 512, 0, stream>>>(h2, Wc, bc, stats + 2, g2, b2, out);
}